// Round 1
// baseline (4801.605 us; speedup 1.0000x reference)
//
#include <hip/hip_runtime.h>

// SimpleAGG: 3-hop graph aggregation, F=1.
// h'[v] = w_self[i]*h[v] + w_neigh[i]*sum_{e: dst[e]==v} h[src[e]]
//
// Inputs: d_in[0]=h (N f32), d_in[1]=src (E i32), d_in[2]=dst (E i32),
//         d_in[3]=w_self (HOPS f32, 1x1 mats), d_in[4]=w_neigh (HOPS f32)
// Output: d_out = h after HOPS hops (N f32)
// Workspace: buf (N f32) + neigh (N f32) = 8 MB.

constexpr int BLK = 256;

__global__ void zero_f32(float* __restrict__ p, int n) {
    int i = blockIdx.x * blockDim.x + threadIdx.x;
    if (i < n) p[i] = 0.0f;
}

// 4 edges per thread: int4 loads of the coalesced index streams,
// L2-resident gather of h[src], device-scope atomic scatter to neigh[dst].
__global__ void scatter_add(const float* __restrict__ h,
                            const int* __restrict__ src,
                            const int* __restrict__ dst,
                            float* __restrict__ neigh,
                            int ne) {
    int i = blockIdx.x * blockDim.x + threadIdx.x;
    int base = i * 4;
    if (base + 3 < ne) {
        int4 s = *reinterpret_cast<const int4*>(src + base);
        int4 d = *reinterpret_cast<const int4*>(dst + base);
        float v0 = h[s.x];
        float v1 = h[s.y];
        float v2 = h[s.z];
        float v3 = h[s.w];
        atomicAdd(&neigh[d.x], v0);
        atomicAdd(&neigh[d.y], v1);
        atomicAdd(&neigh[d.z], v2);
        atomicAdd(&neigh[d.w], v3);
    } else if (base < ne) {
        for (int e = base; e < ne; ++e) {
            atomicAdd(&neigh[dst[e]], h[src[e]]);
        }
    }
}

__global__ void combine(const float* __restrict__ h,
                        const float* __restrict__ neigh,
                        const float* __restrict__ w_self,
                        const float* __restrict__ w_neigh,
                        int hop,
                        float* __restrict__ out, int n) {
    int i = blockIdx.x * blockDim.x + threadIdx.x;
    if (i < n) {
        out[i] = h[i] * w_self[hop] + neigh[i] * w_neigh[hop];
    }
}

extern "C" void kernel_launch(void* const* d_in, const int* in_sizes, int n_in,
                              void* d_out, int out_size, void* d_ws, size_t ws_size,
                              hipStream_t stream) {
    const float* h       = (const float*)d_in[0];
    const int*   src     = (const int*)d_in[1];
    const int*   dst     = (const int*)d_in[2];
    const float* w_self  = (const float*)d_in[3];
    const float* w_neigh = (const float*)d_in[4];
    float* out = (float*)d_out;

    const int n    = in_sizes[0];   // 1,000,000 nodes
    const int ne   = in_sizes[1];   // 32,000,000 edges
    const int hops = in_sizes[3];   // 3 (w_self is [HOPS,1,1])

    float* buf   = (float*)d_ws;    // node state between hops
    float* neigh = buf + n;         // neighbor-sum accumulator

    const int gridN = (n + BLK - 1) / BLK;
    const int gridE = ((ne + 3) / 4 + BLK - 1) / BLK;

    const float* cur = h;
    for (int hop = 0; hop < hops; ++hop) {
        float* nxt = (hop == hops - 1) ? out : buf;
        zero_f32<<<gridN, BLK, 0, stream>>>(neigh, n);
        scatter_add<<<gridE, BLK, 0, stream>>>(cur, src, dst, neigh, ne);
        // in-place safe: combine reads/writes element i only
        combine<<<gridN, BLK, 0, stream>>>(cur, neigh, w_self, w_neigh, hop, nxt, n);
        cur = nxt;
    }
}

// Round 2
// 1285.384 us; speedup vs baseline: 3.7355x; 3.7355x over previous
//
#include <hip/hip_runtime.h>

// SimpleAGG: 3-hop graph aggregation, F=1.
// h'[v] = w_self[i]*h[v] + w_neigh[i]*sum_{e: dst[e]==v} h[src[e]]
//
// Round 2 strategy: device-scope float atomics (32M/hop) were the bottleneck
// (WRITE_SIZE ~1GB/hop = each atomic a memory-side RMW, ~21 G atomics/s).
// Replace with: one-time coarse counting sort of edges by dst>>14 into
// buckets of 16384 nodes; per hop, aggregate bucket slices in 64KB LDS
// accumulators (LDS atomics only), flush dense partials, fused
// reduce+combine. Falls back to the atomic path if ws_size is too small.

constexpr int BLK    = 256;
constexpr int BBITS  = 14;
constexpr int BUCKET = 1 << BBITS;   // 16384 nodes per bucket, 64KB LDS fp32
constexpr int SPLIT  = 8;            // blocks per bucket in agg pass
constexpr int NBLK   = 1024;         // binning blocks
constexpr int NB_MAX = 64;           // max buckets supported by fast path

// ---------------- fast path kernels ----------------

__global__ void hist_kernel(const int* __restrict__ dst, int ne, int chunk,
                            unsigned* __restrict__ counts, int nb) {
    __shared__ unsigned hist[NB_MAX];
    for (int b = threadIdx.x; b < nb; b += blockDim.x) hist[b] = 0;
    __syncthreads();
    int s = blockIdx.x * chunk;
    int e = min(s + chunk, ne);
    if (s < e) {
        int nvec = (e - s) & ~3;
        for (int i = s + threadIdx.x * 4; i < s + nvec; i += blockDim.x * 4) {
            int4 d = *reinterpret_cast<const int4*>(dst + i);
            atomicAdd(&hist[d.x >> BBITS], 1u);
            atomicAdd(&hist[d.y >> BBITS], 1u);
            atomicAdd(&hist[d.z >> BBITS], 1u);
            atomicAdd(&hist[d.w >> BBITS], 1u);
        }
        if (threadIdx.x == 0)
            for (int i = s + nvec; i < e; ++i) atomicAdd(&hist[dst[i] >> BBITS], 1u);
    }
    __syncthreads();
    for (int b = threadIdx.x; b < nb; b += blockDim.x)
        counts[(size_t)b * gridDim.x + blockIdx.x] = hist[b];
}

// exclusive scan over counts[nb*NBLK] (bucket-major), single block of 1024
__global__ void scan_kernel(const unsigned* __restrict__ counts,
                            unsigned* __restrict__ offsets, int tot) {
    __shared__ unsigned sums[1024];
    int t = threadIdx.x;
    int seg = (tot + 1023) >> 10;
    int s = t * seg, e = min(s + seg, tot);
    unsigned acc = 0;
    for (int i = s; i < e; ++i) acc += counts[i];
    sums[t] = acc;
    __syncthreads();
    for (int d = 1; d < 1024; d <<= 1) {
        unsigned v = (t >= d) ? sums[t - d] : 0u;
        __syncthreads();
        sums[t] += v;
        __syncthreads();
    }
    unsigned excl = sums[t] - acc;
    for (int i = s; i < e; ++i) {
        unsigned c = counts[i];
        offsets[i] = excl;
        excl += c;
    }
}

__global__ void bin_kernel(const int* __restrict__ src, const int* __restrict__ dst,
                           int ne, int chunk,
                           const unsigned* __restrict__ offsets, int nblk,
                           unsigned* __restrict__ bsrc, unsigned short* __restrict__ bdl,
                           int nb) {
    __shared__ unsigned cur[NB_MAX];
    for (int b = threadIdx.x; b < nb; b += blockDim.x)
        cur[b] = offsets[(size_t)b * nblk + blockIdx.x];
    __syncthreads();
    int s = blockIdx.x * chunk;
    int e = min(s + chunk, ne);
    if (s >= e) return;
    int nvec = (e - s) & ~3;
    for (int i = s + threadIdx.x * 4; i < s + nvec; i += blockDim.x * 4) {
        int4 sv = *reinterpret_cast<const int4*>(src + i);
        int4 dv = *reinterpret_cast<const int4*>(dst + i);
        unsigned p;
        p = atomicAdd(&cur[dv.x >> BBITS], 1u);
        bsrc[p] = (unsigned)sv.x; bdl[p] = (unsigned short)(dv.x & (BUCKET - 1));
        p = atomicAdd(&cur[dv.y >> BBITS], 1u);
        bsrc[p] = (unsigned)sv.y; bdl[p] = (unsigned short)(dv.y & (BUCKET - 1));
        p = atomicAdd(&cur[dv.z >> BBITS], 1u);
        bsrc[p] = (unsigned)sv.z; bdl[p] = (unsigned short)(dv.z & (BUCKET - 1));
        p = atomicAdd(&cur[dv.w >> BBITS], 1u);
        bsrc[p] = (unsigned)sv.w; bdl[p] = (unsigned short)(dv.w & (BUCKET - 1));
    }
    if (threadIdx.x == 0)
        for (int i = s + nvec; i < e; ++i) {
            unsigned p = atomicAdd(&cur[dst[i] >> BBITS], 1u);
            bsrc[p] = (unsigned)src[i];
            bdl[p]  = (unsigned short)(dst[i] & (BUCKET - 1));
        }
}

__global__ __launch_bounds__(256, 1)
void agg_kernel(const float* __restrict__ curh,
                const unsigned* __restrict__ bsrc, const unsigned short* __restrict__ bdl,
                const unsigned* __restrict__ offsets, int nblk, int ne, int nb,
                float* __restrict__ partials) {
    __shared__ float acc[BUCKET];   // 64 KB
    int b = blockIdx.x / SPLIT;
    int s = blockIdx.x % SPLIT;
    for (int i = threadIdx.x; i < BUCKET; i += blockDim.x) acc[i] = 0.0f;
    __syncthreads();
    unsigned bs = offsets[(size_t)b * nblk];
    unsigned be = (b == nb - 1) ? (unsigned)ne : offsets[(size_t)(b + 1) * nblk];
    unsigned cnt = be - bs;
    unsigned per = (cnt + SPLIT - 1) / SPLIT;
    unsigned ss = bs + (unsigned)s * per;
    unsigned se = min(ss + per, be);
    for (unsigned i = ss + threadIdx.x; i < se; i += blockDim.x) {
        float v = curh[bsrc[i]];
        atomicAdd(&acc[bdl[i]], v);
    }
    __syncthreads();
    float* out = partials + ((size_t)(b * SPLIT + s)) * BUCKET;
    for (int i = threadIdx.x; i < BUCKET; i += blockDim.x) out[i] = acc[i];
}

__global__ void reduce_combine(const float* __restrict__ curh,
                               const float* __restrict__ partials,
                               const float* __restrict__ w_self,
                               const float* __restrict__ w_neigh, int hop,
                               float* __restrict__ out, int n) {
    int i = blockIdx.x * blockDim.x + threadIdx.x;
    if (i >= n) return;
    int b = i >> BBITS, l = i & (BUCKET - 1);
    const float* p = partials + ((size_t)b * SPLIT) * BUCKET + l;
    float sum = 0.0f;
#pragma unroll
    for (int s = 0; s < SPLIT; ++s) sum += p[(size_t)s * BUCKET];
    out[i] = curh[i] * w_self[hop] + sum * w_neigh[hop];
}

// ---------------- fallback (round-1 atomic path) ----------------

__global__ void zero_f32(float* __restrict__ p, int n) {
    int i = blockIdx.x * blockDim.x + threadIdx.x;
    if (i < n) p[i] = 0.0f;
}

__global__ void scatter_add(const float* __restrict__ h, const int* __restrict__ src,
                            const int* __restrict__ dst, float* __restrict__ neigh, int ne) {
    int i = blockIdx.x * blockDim.x + threadIdx.x;
    int base = i * 4;
    if (base + 3 < ne) {
        int4 s = *reinterpret_cast<const int4*>(src + base);
        int4 d = *reinterpret_cast<const int4*>(dst + base);
        atomicAdd(&neigh[d.x], h[s.x]);
        atomicAdd(&neigh[d.y], h[s.y]);
        atomicAdd(&neigh[d.z], h[s.z]);
        atomicAdd(&neigh[d.w], h[s.w]);
    } else if (base < ne) {
        for (int e = base; e < ne; ++e) atomicAdd(&neigh[dst[e]], h[src[e]]);
    }
}

__global__ void combine(const float* __restrict__ h, const float* __restrict__ neigh,
                        const float* __restrict__ w_self, const float* __restrict__ w_neigh,
                        int hop, float* __restrict__ out, int n) {
    int i = blockIdx.x * blockDim.x + threadIdx.x;
    if (i < n) out[i] = h[i] * w_self[hop] + neigh[i] * w_neigh[hop];
}

// ---------------- launch ----------------

extern "C" void kernel_launch(void* const* d_in, const int* in_sizes, int n_in,
                              void* d_out, int out_size, void* d_ws, size_t ws_size,
                              hipStream_t stream) {
    const float* h       = (const float*)d_in[0];
    const int*   src     = (const int*)d_in[1];
    const int*   dst     = (const int*)d_in[2];
    const float* w_self  = (const float*)d_in[3];
    const float* w_neigh = (const float*)d_in[4];
    float* out = (float*)d_out;

    const int n    = in_sizes[0];
    const int ne   = in_sizes[1];
    const int hops = in_sizes[3];

    const int nb = (n + BUCKET - 1) >> BBITS;

    // workspace layout (256B-aligned regions)
    size_t off = 0;
    auto take = [&](size_t bytes) { size_t o = off; off = (off + bytes + 255) & ~255UL; return o; };
    size_t o_bsrc     = take((size_t)ne * 4);
    size_t o_bdl      = take((size_t)ne * 2);
    size_t o_counts   = take((size_t)nb * NBLK * 4);
    size_t o_offsets  = take((size_t)nb * NBLK * 4);
    size_t o_partials = take((size_t)nb * SPLIT * BUCKET * 4);
    size_t o_buf      = take((size_t)n * 4);
    size_t needed = off;

    char* ws = (char*)d_ws;
    bool fast = (ws_size >= needed) && (nb <= NB_MAX);

    if (fast) {
        unsigned*       counts   = (unsigned*)(ws + o_counts);
        unsigned*       offsets  = (unsigned*)(ws + o_offsets);
        unsigned*       bsrc     = (unsigned*)(ws + o_bsrc);
        unsigned short* bdl      = (unsigned short*)(ws + o_bdl);
        float*          partials = (float*)(ws + o_partials);
        float*          buf      = (float*)(ws + o_buf);

        int chunk = (((ne + NBLK - 1) / NBLK) + 3) & ~3;   // multiple of 4 for int4
        int tot = nb * NBLK;

        hist_kernel<<<NBLK, BLK, 0, stream>>>(dst, ne, chunk, counts, nb);
        scan_kernel<<<1, 1024, 0, stream>>>(counts, offsets, tot);
        bin_kernel<<<NBLK, BLK, 0, stream>>>(src, dst, ne, chunk, offsets, NBLK, bsrc, bdl, nb);

        const int gridN = (n + BLK - 1) / BLK;
        const float* cur = h;
        for (int hop = 0; hop < hops; ++hop) {
            float* nxt = (hop == hops - 1) ? out : buf;
            agg_kernel<<<nb * SPLIT, BLK, 0, stream>>>(cur, bsrc, bdl, offsets, NBLK, ne, nb, partials);
            reduce_combine<<<gridN, BLK, 0, stream>>>(cur, partials, w_self, w_neigh, hop, nxt, n);
            cur = nxt;   // in-place safe after hop 0
        }
    } else {
        float* buf   = (float*)d_ws;
        float* neigh = buf + n;
        const int gridN = (n + BLK - 1) / BLK;
        const int gridE = ((ne + 3) / 4 + BLK - 1) / BLK;
        const float* cur = h;
        for (int hop = 0; hop < hops; ++hop) {
            float* nxt = (hop == hops - 1) ? out : buf;
            zero_f32<<<gridN, BLK, 0, stream>>>(neigh, n);
            scatter_add<<<gridE, BLK, 0, stream>>>(cur, src, dst, neigh, ne);
            combine<<<gridN, BLK, 0, stream>>>(cur, neigh, w_self, w_neigh, hop, nxt, n);
            cur = nxt;
        }
    }
}

// Round 3
// 987.077 us; speedup vs baseline: 4.8645x; 1.3022x over previous
//
#include <hip/hip_runtime.h>

// SimpleAGG: 3-hop graph aggregation, F=1.
// h'[v] = w_self[i]*h[v] + w_neigh[i]*sum_{e: dst[e]==v} h[src[e]]
//
// Round 3: pack edges into u32 records ((dst&4095)<<20 | src, needs n<=2^20),
// bucket = dst>>12 (245 buckets, 16KB LDS accumulator in agg -> 8 blocks/CU).
// bin_kernel counting-sorts 8192-edge tiles in LDS and writes contiguous
// per-bucket runs (coalesced bursts) into exact global regions reserved via
// per-bucket cursors. hist+scan give exact regions. Fallback: atomic path.

constexpr int BLK     = 256;
constexpr int BBITS   = 12;
constexpr int BUCKET  = 1 << BBITS;   // 4096 nodes, 16KB fp32 LDS
constexpr int NB_MAX  = 256;          // bucket ids fit u8, scan width 256
constexpr int SPLIT   = 8;            // agg blocks per bucket
constexpr int TILE    = 8192;         // edges per bin block (32KB rec + 8KB bid LDS)
constexpr int HBLOCKS = 1024;

// ---------------- fast path ----------------

__global__ void zero_u32(unsigned* __restrict__ p, int n) {
    int i = blockIdx.x * blockDim.x + threadIdx.x;
    if (i < n) p[i] = 0u;
}

__global__ void hist_kernel(const int* __restrict__ dst, int ne,
                            unsigned* __restrict__ count, int nb) {
    __shared__ unsigned hist[NB_MAX];
    for (int b = threadIdx.x; b < NB_MAX; b += blockDim.x) hist[b] = 0u;
    __syncthreads();
    const int4* dst4 = reinterpret_cast<const int4*>(dst);
    int nvec = ne >> 2;
    for (int i = blockIdx.x * blockDim.x + threadIdx.x; i < nvec;
         i += gridDim.x * blockDim.x) {
        int4 d = dst4[i];
        atomicAdd(&hist[d.x >> BBITS], 1u);
        atomicAdd(&hist[d.y >> BBITS], 1u);
        atomicAdd(&hist[d.z >> BBITS], 1u);
        atomicAdd(&hist[d.w >> BBITS], 1u);
    }
    if (blockIdx.x == 0 && threadIdx.x == 0)
        for (int i = nvec << 2; i < ne; ++i) atomicAdd(&hist[dst[i] >> BBITS], 1u);
    __syncthreads();
    for (int b = threadIdx.x; b < nb; b += blockDim.x)
        if (hist[b]) atomicAdd(&count[b], hist[b]);
}

// single block of NB_MAX threads: exclusive scan -> offsets[0..nb], cursor
__global__ void scan_kernel(const unsigned* __restrict__ count,
                            unsigned* __restrict__ offsets,
                            unsigned* __restrict__ cursor, int nb) {
    __shared__ unsigned s[NB_MAX];
    int t = threadIdx.x;
    unsigned v = (t < nb) ? count[t] : 0u;
    s[t] = v;
    __syncthreads();
    for (int d = 1; d < NB_MAX; d <<= 1) {
        unsigned u = (t >= d) ? s[t - d] : 0u;
        __syncthreads();
        s[t] += u;
        __syncthreads();
    }
    unsigned excl = s[t] - v;
    if (t < nb) { offsets[t] = excl; cursor[t] = excl; }
    if (t == nb - 1) offsets[nb] = excl + v;
}

__global__ __launch_bounds__(256)
void bin_kernel(const int* __restrict__ src, const int* __restrict__ dst, int ne,
                unsigned* __restrict__ cursor, unsigned* __restrict__ recs) {
    __shared__ unsigned hist[NB_MAX];
    __shared__ unsigned start[NB_MAX];
    __shared__ unsigned lpos[NB_MAX];
    __shared__ unsigned gbase[NB_MAX];
    __shared__ unsigned rec[TILE];
    __shared__ unsigned char bid[TILE];

    int base = blockIdx.x * TILE;
    int cnt = min(TILE, ne - base);
    if (cnt <= 0) return;

    for (int b = threadIdx.x; b < NB_MAX; b += blockDim.x) hist[b] = 0u;
    __syncthreads();

    int nvec = cnt & ~3;
    const int4* dst4 = reinterpret_cast<const int4*>(dst + base);
    const int4* src4 = reinterpret_cast<const int4*>(src + base);

    // phase 1: tile histogram
    for (int i = threadIdx.x; i < (nvec >> 2); i += blockDim.x) {
        int4 d = dst4[i];
        atomicAdd(&hist[d.x >> BBITS], 1u);
        atomicAdd(&hist[d.y >> BBITS], 1u);
        atomicAdd(&hist[d.z >> BBITS], 1u);
        atomicAdd(&hist[d.w >> BBITS], 1u);
    }
    if (threadIdx.x == 0)
        for (int i = nvec; i < cnt; ++i) atomicAdd(&hist[dst[base + i] >> BBITS], 1u);
    __syncthreads();

    // phase 2: scan hist -> start (exclusive), reserve global runs
    {
        int t = threadIdx.x;           // blockDim == NB_MAX == 256
        unsigned v = hist[t];
        start[t] = v;
        __syncthreads();
        for (int d = 1; d < NB_MAX; d <<= 1) {
            unsigned u = (t >= d) ? start[t - d] : 0u;
            __syncthreads();
            start[t] += u;
            __syncthreads();
        }
        unsigned excl = start[t] - v;
        __syncthreads();
        start[t] = excl;
        lpos[t]  = excl;
        if (v) gbase[t] = atomicAdd(&cursor[t], v);
        __syncthreads();
    }

    // phase 3: place records into LDS sorted by bucket
    for (int i = threadIdx.x; i < (nvec >> 2); i += blockDim.x) {
        int4 d = dst4[i];
        int4 s = src4[i];
        int dd[4] = {d.x, d.y, d.z, d.w};
        int ss[4] = {s.x, s.y, s.z, s.w};
#pragma unroll
        for (int k = 0; k < 4; ++k) {
            int b = dd[k] >> BBITS;
            unsigned p = atomicAdd(&lpos[b], 1u);
            rec[p] = ((unsigned)(dd[k] & (BUCKET - 1)) << 20) | (unsigned)ss[k];
            bid[p] = (unsigned char)b;
        }
    }
    if (threadIdx.x == 0)
        for (int i = nvec; i < cnt; ++i) {
            int dd = dst[base + i], ss = src[base + i];
            int b = dd >> BBITS;
            unsigned p = atomicAdd(&lpos[b], 1u);
            rec[p] = ((unsigned)(dd & (BUCKET - 1)) << 20) | (unsigned)ss;
            bid[p] = (unsigned char)b;
        }
    __syncthreads();

    // phase 4: coalesced copy-out of contiguous runs
    for (int i = threadIdx.x; i < cnt; i += blockDim.x) {
        int b = bid[i];
        recs[gbase[b] + ((unsigned)i - start[b])] = rec[i];
    }
}

__global__ __launch_bounds__(256)
void agg_kernel(const float* __restrict__ curh,
                const unsigned* __restrict__ recs,
                const unsigned* __restrict__ offsets,
                float* __restrict__ partials) {
    __shared__ float acc[BUCKET];   // 16 KB
    int b = blockIdx.x / SPLIT;
    int s = blockIdx.x % SPLIT;
    for (int i = threadIdx.x; i < BUCKET; i += blockDim.x) acc[i] = 0.0f;
    __syncthreads();
    unsigned bs = offsets[b], be = offsets[b + 1];
    unsigned cnt = be - bs;
    unsigned per = (cnt + SPLIT - 1) / SPLIT;
    unsigned ss = bs + (unsigned)s * per;
    unsigned se = min(ss + per, be);
    for (unsigned i = ss + threadIdx.x; i < se; i += blockDim.x) {
        unsigned r = recs[i];
        float v = curh[r & 0xFFFFFu];
        atomicAdd(&acc[r >> 20], v);
    }
    __syncthreads();
    float* out = partials + ((size_t)blockIdx.x) * BUCKET;
    for (int i = threadIdx.x; i < BUCKET; i += blockDim.x) out[i] = acc[i];
}

__global__ void reduce_combine(const float* __restrict__ curh,
                               const float* __restrict__ partials,
                               const float* __restrict__ w_self,
                               const float* __restrict__ w_neigh, int hop,
                               float* __restrict__ out, int n) {
    int i = blockIdx.x * blockDim.x + threadIdx.x;
    if (i >= n) return;
    int b = i >> BBITS, l = i & (BUCKET - 1);
    const float* p = partials + ((size_t)b * SPLIT) * BUCKET + l;
    float sum = 0.0f;
#pragma unroll
    for (int s = 0; s < SPLIT; ++s) sum += p[(size_t)s * BUCKET];
    out[i] = curh[i] * w_self[hop] + sum * w_neigh[hop];
}

// ---------------- fallback (atomic path) ----------------

__global__ void zero_f32(float* __restrict__ p, int n) {
    int i = blockIdx.x * blockDim.x + threadIdx.x;
    if (i < n) p[i] = 0.0f;
}

__global__ void scatter_add(const float* __restrict__ h, const int* __restrict__ src,
                            const int* __restrict__ dst, float* __restrict__ neigh, int ne) {
    int i = blockIdx.x * blockDim.x + threadIdx.x;
    int base = i * 4;
    if (base + 3 < ne) {
        int4 s = *reinterpret_cast<const int4*>(src + base);
        int4 d = *reinterpret_cast<const int4*>(dst + base);
        atomicAdd(&neigh[d.x], h[s.x]);
        atomicAdd(&neigh[d.y], h[s.y]);
        atomicAdd(&neigh[d.z], h[s.z]);
        atomicAdd(&neigh[d.w], h[s.w]);
    } else if (base < ne) {
        for (int e = base; e < ne; ++e) atomicAdd(&neigh[dst[e]], h[src[e]]);
    }
}

__global__ void combine(const float* __restrict__ h, const float* __restrict__ neigh,
                        const float* __restrict__ w_self, const float* __restrict__ w_neigh,
                        int hop, float* __restrict__ out, int n) {
    int i = blockIdx.x * blockDim.x + threadIdx.x;
    if (i < n) out[i] = h[i] * w_self[hop] + neigh[i] * w_neigh[hop];
}

// ---------------- launch ----------------

extern "C" void kernel_launch(void* const* d_in, const int* in_sizes, int n_in,
                              void* d_out, int out_size, void* d_ws, size_t ws_size,
                              hipStream_t stream) {
    const float* h       = (const float*)d_in[0];
    const int*   src     = (const int*)d_in[1];
    const int*   dst     = (const int*)d_in[2];
    const float* w_self  = (const float*)d_in[3];
    const float* w_neigh = (const float*)d_in[4];
    float* out = (float*)d_out;

    const int n    = in_sizes[0];
    const int ne   = in_sizes[1];
    const int hops = in_sizes[3];

    const int nb = (n + BUCKET - 1) >> BBITS;

    size_t off = 0;
    auto take = [&](size_t bytes) { size_t o = off; off = (off + bytes + 255) & ~255UL; return o; };
    size_t o_recs     = take((size_t)ne * 4);
    size_t o_count    = take((size_t)NB_MAX * 4);
    size_t o_offsets  = take((size_t)(NB_MAX + 1) * 4);
    size_t o_cursor   = take((size_t)NB_MAX * 4);
    size_t o_partials = take((size_t)nb * SPLIT * BUCKET * 4);
    size_t o_buf      = take((size_t)n * 4);
    size_t needed = off;

    char* ws = (char*)d_ws;
    bool fast = (ws_size >= needed) && (nb <= NB_MAX) && (n <= (1 << 20));

    if (fast) {
        unsigned* recs     = (unsigned*)(ws + o_recs);
        unsigned* count    = (unsigned*)(ws + o_count);
        unsigned* offsets  = (unsigned*)(ws + o_offsets);
        unsigned* cursor   = (unsigned*)(ws + o_cursor);
        float*    partials = (float*)(ws + o_partials);
        float*    buf      = (float*)(ws + o_buf);

        zero_u32<<<1, NB_MAX, 0, stream>>>(count, NB_MAX);
        hist_kernel<<<HBLOCKS, BLK, 0, stream>>>(dst, ne, count, nb);
        scan_kernel<<<1, NB_MAX, 0, stream>>>(count, offsets, cursor, nb);
        bin_kernel<<<(ne + TILE - 1) / TILE, BLK, 0, stream>>>(src, dst, ne, cursor, recs);

        const int gridN = (n + BLK - 1) / BLK;
        const float* cur = h;
        for (int hop = 0; hop < hops; ++hop) {
            float* nxt = (hop == hops - 1) ? out : buf;
            agg_kernel<<<nb * SPLIT, BLK, 0, stream>>>(cur, recs, offsets, partials);
            reduce_combine<<<gridN, BLK, 0, stream>>>(cur, partials, w_self, w_neigh, hop, nxt, n);
            cur = nxt;
        }
    } else {
        float* buf   = (float*)d_ws;
        float* neigh = buf + n;
        const int gridN = (n + BLK - 1) / BLK;
        const int gridE = ((ne + 3) / 4 + BLK - 1) / BLK;
        const float* cur = h;
        for (int hop = 0; hop < hops; ++hop) {
            float* nxt = (hop == hops - 1) ? out : buf;
            zero_f32<<<gridN, BLK, 0, stream>>>(neigh, n);
            scatter_add<<<gridE, BLK, 0, stream>>>(cur, src, dst, neigh, ne);
            combine<<<gridN, BLK, 0, stream>>>(cur, neigh, w_self, w_neigh, hop, nxt, n);
            cur = nxt;
        }
    }
}

// Round 5
// 935.514 us; speedup vs baseline: 5.1326x; 1.0551x over previous
//
#include <hip/hip_runtime.h>

// SimpleAGG: 3-hop graph aggregation, F=1.
// h'[v] = w_self[i]*h[v] + w_neigh[i]*sum_{e: dst[e]==v} h[src[e]]
//
// Round 5 (= round-4 plan, compile-fixed): __builtin_nontemporal_load needs
// Clang ext_vector types, not HIP_vector_type structs -> use u32x4/f32x4.
// - agg: 1024-thr blocks, SPLIT=2 (490 blocks, 2/CU resident = 32 waves/CU),
//   uint4 rec loads -> 4 independent gathers per iter (4x MLP),
//   nontemporal rec loads (keep curh L2-resident; FETCH was 212MB vs 128).
// - bucket regions 16B-aligned (padded scan) for aligned uint4.
// - reduce_combine float4-vectorized; partials NT store/load.
// - hist: 4-way replicated LDS counters.

typedef unsigned u32x4 __attribute__((ext_vector_type(4)));
typedef float    f32x4 __attribute__((ext_vector_type(4)));

constexpr int BLK     = 256;
constexpr int BBITS   = 12;
constexpr int BUCKET  = 1 << BBITS;   // 4096 nodes, 16KB fp32 LDS
constexpr int NB_MAX  = 256;          // bucket ids fit u8
constexpr int SPLIT   = 2;            // agg blocks per bucket (1024 thr each)
constexpr int TILE    = 8192;         // edges per bin block
constexpr int HBLOCKS = 1024;

// ---------------- fast path ----------------

__global__ void zero_u32(unsigned* __restrict__ p, int n) {
    int i = blockIdx.x * blockDim.x + threadIdx.x;
    if (i < n) p[i] = 0u;
}

__global__ void hist_kernel(const int* __restrict__ dst, int ne,
                            unsigned* __restrict__ count, int nb) {
    __shared__ unsigned hist[NB_MAX * 4];
    for (int b = threadIdx.x; b < NB_MAX * 4; b += blockDim.x) hist[b] = 0u;
    __syncthreads();
    const u32x4* dst4 = reinterpret_cast<const u32x4*>(dst);
    int nvec = ne >> 2;
    int sub = threadIdx.x & 3;
    for (int i = blockIdx.x * blockDim.x + threadIdx.x; i < nvec;
         i += gridDim.x * blockDim.x) {
        u32x4 d = __builtin_nontemporal_load(dst4 + i);
        atomicAdd(&hist[((d.x >> BBITS) << 2) | sub], 1u);
        atomicAdd(&hist[((d.y >> BBITS) << 2) | sub], 1u);
        atomicAdd(&hist[((d.z >> BBITS) << 2) | sub], 1u);
        atomicAdd(&hist[((d.w >> BBITS) << 2) | sub], 1u);
    }
    if (blockIdx.x == 0 && threadIdx.x == 0)
        for (int i = nvec << 2; i < ne; ++i)
            atomicAdd(&hist[(((unsigned)dst[i] >> BBITS) << 2)], 1u);
    __syncthreads();
    for (int b = threadIdx.x; b < nb; b += blockDim.x) {
        unsigned v = hist[b * 4] + hist[b * 4 + 1] + hist[b * 4 + 2] + hist[b * 4 + 3];
        if (v) atomicAdd(&count[b], v);
    }
}

// single block of NB_MAX threads: 16B-aligned exclusive scan of counts
__global__ void scan_kernel(const unsigned* __restrict__ count,
                            unsigned* __restrict__ offsets,
                            unsigned* __restrict__ cursor, int nb) {
    __shared__ unsigned s[NB_MAX];
    int t = threadIdx.x;
    unsigned v  = (t < nb) ? count[t] : 0u;
    unsigned pv = (v + 3u) & ~3u;        // pad region to multiple of 4 recs
    s[t] = pv;
    __syncthreads();
    for (int d = 1; d < NB_MAX; d <<= 1) {
        unsigned u = (t >= d) ? s[t - d] : 0u;
        __syncthreads();
        s[t] += u;
        __syncthreads();
    }
    unsigned excl = s[t] - pv;
    if (t < nb) { offsets[t] = excl; cursor[t] = excl; }
}

__global__ __launch_bounds__(256)
void bin_kernel(const int* __restrict__ src, const int* __restrict__ dst, int ne,
                unsigned* __restrict__ cursor, unsigned* __restrict__ recs) {
    __shared__ unsigned hist[NB_MAX];
    __shared__ unsigned start[NB_MAX];
    __shared__ unsigned lpos[NB_MAX];
    __shared__ unsigned gbase[NB_MAX];
    __shared__ unsigned rec[TILE];
    __shared__ unsigned char bid[TILE];

    int base = blockIdx.x * TILE;
    int cnt = min(TILE, ne - base);
    if (cnt <= 0) return;

    for (int b = threadIdx.x; b < NB_MAX; b += blockDim.x) hist[b] = 0u;
    __syncthreads();

    int nvec = cnt & ~3;
    const u32x4* dst4 = reinterpret_cast<const u32x4*>(dst + base);
    const u32x4* src4 = reinterpret_cast<const u32x4*>(src + base);

    // phase 1: tile histogram
    for (int i = threadIdx.x; i < (nvec >> 2); i += blockDim.x) {
        u32x4 d = dst4[i];
        atomicAdd(&hist[d.x >> BBITS], 1u);
        atomicAdd(&hist[d.y >> BBITS], 1u);
        atomicAdd(&hist[d.z >> BBITS], 1u);
        atomicAdd(&hist[d.w >> BBITS], 1u);
    }
    if (threadIdx.x == 0)
        for (int i = nvec; i < cnt; ++i)
            atomicAdd(&hist[(unsigned)dst[base + i] >> BBITS], 1u);
    __syncthreads();

    // phase 2: scan hist -> start (exclusive), reserve global runs
    {
        int t = threadIdx.x;           // blockDim == NB_MAX == 256
        unsigned v = hist[t];
        start[t] = v;
        __syncthreads();
        for (int d = 1; d < NB_MAX; d <<= 1) {
            unsigned u = (t >= d) ? start[t - d] : 0u;
            __syncthreads();
            start[t] += u;
            __syncthreads();
        }
        unsigned excl = start[t] - v;
        __syncthreads();
        start[t] = excl;
        lpos[t]  = excl;
        if (v) gbase[t] = atomicAdd(&cursor[t], v);
        __syncthreads();
    }

    // phase 3: place records into LDS sorted by bucket (NT: last read of tile)
    for (int i = threadIdx.x; i < (nvec >> 2); i += blockDim.x) {
        u32x4 d = __builtin_nontemporal_load(dst4 + i);
        u32x4 s = __builtin_nontemporal_load(src4 + i);
        unsigned dd[4] = {d.x, d.y, d.z, d.w};
        unsigned ss[4] = {s.x, s.y, s.z, s.w};
#pragma unroll
        for (int k = 0; k < 4; ++k) {
            unsigned b = dd[k] >> BBITS;
            unsigned p = atomicAdd(&lpos[b], 1u);
            rec[p] = ((dd[k] & (BUCKET - 1)) << 20) | ss[k];
            bid[p] = (unsigned char)b;
        }
    }
    if (threadIdx.x == 0)
        for (int i = nvec; i < cnt; ++i) {
            unsigned dd = (unsigned)dst[base + i], ss = (unsigned)src[base + i];
            unsigned b = dd >> BBITS;
            unsigned p = atomicAdd(&lpos[b], 1u);
            rec[p] = ((dd & (BUCKET - 1)) << 20) | ss;
            bid[p] = (unsigned char)b;
        }
    __syncthreads();

    // phase 4: coalesced copy-out of contiguous runs
    for (int i = threadIdx.x; i < cnt; i += blockDim.x) {
        int b = bid[i];
        recs[gbase[b] + ((unsigned)i - start[b])] = rec[i];
    }
}

__global__ __launch_bounds__(1024, 8)
void agg_kernel(const float* __restrict__ curh,
                const unsigned* __restrict__ recs,
                const unsigned* __restrict__ offsets,
                const unsigned* __restrict__ count,
                float* __restrict__ partials) {
    __shared__ float acc[BUCKET];   // 16 KB
    int b = blockIdx.x >> 1;
    int s = blockIdx.x & 1;
    for (int i = threadIdx.x; i < BUCKET; i += 1024) acc[i] = 0.0f;
    __syncthreads();
    unsigned bs  = offsets[b];          // 16B-aligned
    unsigned cnt = count[b];
    unsigned half = (cnt >> 1) & ~3u;   // keep both splits 16B-aligned
    unsigned ss = bs + (s ? half : 0u);
    unsigned sc = s ? (cnt - half) : half;
    unsigned n4 = sc >> 2;
    const u32x4* rq = reinterpret_cast<const u32x4*>(recs + ss);
    for (unsigned q = threadIdx.x; q < n4; q += 1024) {
        u32x4 r = __builtin_nontemporal_load(rq + q);
        float v0 = curh[r.x & 0xFFFFFu];
        float v1 = curh[r.y & 0xFFFFFu];
        float v2 = curh[r.z & 0xFFFFFu];
        float v3 = curh[r.w & 0xFFFFFu];
        atomicAdd(&acc[r.x >> 20], v0);
        atomicAdd(&acc[r.y >> 20], v1);
        atomicAdd(&acc[r.z >> 20], v2);
        atomicAdd(&acc[r.w >> 20], v3);
    }
    unsigned tb = ss + (n4 << 2);
    unsigned rem = sc & 3u;
    if (threadIdx.x < rem) {
        unsigned r = recs[tb + threadIdx.x];
        atomicAdd(&acc[r >> 20], curh[r & 0xFFFFFu]);
    }
    __syncthreads();
    float* outp = partials + ((size_t)blockIdx.x) * BUCKET;
    for (int i = threadIdx.x; i < BUCKET; i += 1024)
        __builtin_nontemporal_store(acc[i], outp + i);
}

__global__ void reduce_combine(const float* __restrict__ curh,
                               const float* __restrict__ partials,
                               const float* __restrict__ w_self,
                               const float* __restrict__ w_neigh, int hop,
                               float* __restrict__ out, int n) {
    int i = blockIdx.x * blockDim.x + threadIdx.x;   // quad index
    int nq = (n + 3) >> 2;
    if (i >= nq) return;
    int node = i << 2;
    float wsv = w_self[hop], wnv = w_neigh[hop];
    int b = node >> BBITS, l = node & (BUCKET - 1);
    const float* p0 = partials + ((size_t)b * SPLIT) * BUCKET + l;
    const float* p1 = p0 + BUCKET;
    if (node + 3 < n) {
        f32x4 a = __builtin_nontemporal_load(reinterpret_cast<const f32x4*>(p0));
        f32x4 c = __builtin_nontemporal_load(reinterpret_cast<const f32x4*>(p1));
        f32x4 hh = *reinterpret_cast<const f32x4*>(curh + node);
        f32x4 o = hh * wsv + (a + c) * wnv;
        *reinterpret_cast<f32x4*>(out + node) = o;
    } else {
        for (int j = node; j < n; ++j) {
            int bb = j >> BBITS, ll = j & (BUCKET - 1);
            const float* pp = partials + ((size_t)bb * SPLIT) * BUCKET + ll;
            out[j] = curh[j] * wsv + (pp[0] + pp[BUCKET]) * wnv;
        }
    }
}

// ---------------- fallback (atomic path) ----------------

__global__ void zero_f32(float* __restrict__ p, int n) {
    int i = blockIdx.x * blockDim.x + threadIdx.x;
    if (i < n) p[i] = 0.0f;
}

__global__ void scatter_add(const float* __restrict__ h, const int* __restrict__ src,
                            const int* __restrict__ dst, float* __restrict__ neigh, int ne) {
    int i = blockIdx.x * blockDim.x + threadIdx.x;
    int base = i * 4;
    if (base + 3 < ne) {
        int4 s = *reinterpret_cast<const int4*>(src + base);
        int4 d = *reinterpret_cast<const int4*>(dst + base);
        atomicAdd(&neigh[d.x], h[s.x]);
        atomicAdd(&neigh[d.y], h[s.y]);
        atomicAdd(&neigh[d.z], h[s.z]);
        atomicAdd(&neigh[d.w], h[s.w]);
    } else if (base < ne) {
        for (int e = base; e < ne; ++e) atomicAdd(&neigh[dst[e]], h[src[e]]);
    }
}

__global__ void combine(const float* __restrict__ h, const float* __restrict__ neigh,
                        const float* __restrict__ w_self, const float* __restrict__ w_neigh,
                        int hop, float* __restrict__ out, int n) {
    int i = blockIdx.x * blockDim.x + threadIdx.x;
    if (i < n) out[i] = h[i] * w_self[hop] + neigh[i] * w_neigh[hop];
}

// ---------------- launch ----------------

extern "C" void kernel_launch(void* const* d_in, const int* in_sizes, int n_in,
                              void* d_out, int out_size, void* d_ws, size_t ws_size,
                              hipStream_t stream) {
    const float* h       = (const float*)d_in[0];
    const int*   src     = (const int*)d_in[1];
    const int*   dst     = (const int*)d_in[2];
    const float* w_self  = (const float*)d_in[3];
    const float* w_neigh = (const float*)d_in[4];
    float* out = (float*)d_out;

    const int n    = in_sizes[0];
    const int ne   = in_sizes[1];
    const int hops = in_sizes[3];

    const int nb = (n + BUCKET - 1) >> BBITS;

    size_t off = 0;
    auto take = [&](size_t bytes) { size_t o = off; off = (off + bytes + 255) & ~255UL; return o; };
    size_t o_recs     = take(((size_t)ne + 4 * NB_MAX) * 4);   // +alignment padding
    size_t o_count    = take((size_t)NB_MAX * 4);
    size_t o_offsets  = take((size_t)NB_MAX * 4);
    size_t o_cursor   = take((size_t)NB_MAX * 4);
    size_t o_partials = take((size_t)nb * SPLIT * BUCKET * 4);
    size_t o_buf      = take((size_t)n * 4);
    size_t needed = off;

    char* ws = (char*)d_ws;
    bool fast = (ws_size >= needed) && (nb <= NB_MAX) && (n <= (1 << 20));

    if (fast) {
        unsigned* recs     = (unsigned*)(ws + o_recs);
        unsigned* count    = (unsigned*)(ws + o_count);
        unsigned* offsets  = (unsigned*)(ws + o_offsets);
        unsigned* cursor   = (unsigned*)(ws + o_cursor);
        float*    partials = (float*)(ws + o_partials);
        float*    buf      = (float*)(ws + o_buf);

        zero_u32<<<1, NB_MAX, 0, stream>>>(count, NB_MAX);
        hist_kernel<<<HBLOCKS, BLK, 0, stream>>>(dst, ne, count, nb);
        scan_kernel<<<1, NB_MAX, 0, stream>>>(count, offsets, cursor, nb);
        bin_kernel<<<(ne + TILE - 1) / TILE, BLK, 0, stream>>>(src, dst, ne, cursor, recs);

        const int nq = (n + 3) >> 2;
        const int gridQ = (nq + BLK - 1) / BLK;
        const float* cur = h;
        for (int hop = 0; hop < hops; ++hop) {
            float* nxt = (hop == hops - 1) ? out : buf;
            agg_kernel<<<nb * SPLIT, 1024, 0, stream>>>(cur, recs, offsets, count, partials);
            reduce_combine<<<gridQ, BLK, 0, stream>>>(cur, partials, w_self, w_neigh, hop, nxt, n);
            cur = nxt;
        }
    } else {
        float* buf   = (float*)d_ws;
        float* neigh = buf + n;
        const int gridN = (n + BLK - 1) / BLK;
        const int gridE = ((ne + 3) / 4 + BLK - 1) / BLK;
        const float* cur = h;
        for (int hop = 0; hop < hops; ++hop) {
            float* nxt = (hop == hops - 1) ? out : buf;
            zero_f32<<<gridN, BLK, 0, stream>>>(neigh, n);
            scatter_add<<<gridE, BLK, 0, stream>>>(cur, src, dst, neigh, ne);
            combine<<<gridN, BLK, 0, stream>>>(cur, neigh, w_self, w_neigh, hop, nxt, n);
            cur = nxt;
        }
    }
}